// Round 2
// baseline (779.279 us; speedup 1.0000x reference)
//
#include <hip/hip_runtime.h>
#include <hip/hip_bf16.h>

// Problem dims
#define V_ 50000
#define E_ 300
#define H_ 800
#define K_ 128
#define B_ 131072

typedef float  f32x4 __attribute__((ext_vector_type(4)));
typedef float  f32x2 __attribute__((ext_vector_type(2)));
typedef int    i32x4 __attribute__((ext_vector_type(4)));
typedef unsigned int u32x2 __attribute__((ext_vector_type(2)));
typedef __bf16 bf16x8 __attribute__((ext_vector_type(8)));

#define LOG2E 1.4426950408889634f

// ---------------- ws layout (bytes) ----------------
static constexpr size_t OFF_ETB    = 0;                                  // bf16 [50048][128]
static constexpr size_t SZ_ETB     = (size_t)50048 * 128 * 2;            // 12,812,288
static constexpr size_t OFF_COLSUM = SZ_ETB;                             // 128 f32
static constexpr size_t OFF_PART   = OFF_COLSUM + 512;                   // partial[0]=loss, [1]=kld
static constexpr size_t OFF_RHOP   = OFF_COLSUM + 1024;                  // 3128 rowfrags x 10 ks x 1KB bf16
static constexpr size_t SZ_RHOP    = (size_t)3128 * 10 * 1024;
static constexpr size_t OFF_Q1P    = OFF_RHOP + SZ_RHOP;                 // 50x10 bf16 frags (1KB each)
static constexpr size_t OFF_Q2P8   = OFF_Q1P + (size_t)500 * 1024;       // 50x25 fp8 frags (512B each)
static constexpr size_t OFF_HEADP8 = OFF_Q2P8 + (size_t)1250 * 512;      // 16x25 fp8 frags (mu 0-7, ls 8-15)
static constexpr size_t OFF_ALP    = OFF_HEADP8 + (size_t)400 * 512;     // 8x10 bf16 frags

static __device__ __forceinline__ f32x4 mfma_bf16(i32x4 a, i32x4 b, f32x4 c) {
  return __builtin_amdgcn_mfma_f32_16x16x32_bf16(
      __builtin_bit_cast(bf16x8, a), __builtin_bit_cast(bf16x8, b), c, 0, 0, 0);
}
static __device__ __forceinline__ f32x4 mfma_fp8(long a, long b, f32x4 c) {
  return __builtin_amdgcn_mfma_f32_16x16x32_fp8_fp8(a, b, c, 0, 0, 0);
}

static __device__ __forceinline__ unsigned int cvt_pk_bf16(float a, float b) {
  unsigned int d;
  asm volatile("v_cvt_pk_bf16_f32 %0, %1, %2" : "=v"(d) : "v"(a), "v"(b));
  return d;
}
static __device__ __forceinline__ unsigned int pk_fp8x4(float a, float b, float c, float d) {
  int w = __builtin_amdgcn_cvt_pk_fp8_f32(a, b, 0, false);
  w = __builtin_amdgcn_cvt_pk_fp8_f32(c, d, w, true);
  return (unsigned int)w;
}

static __device__ __forceinline__ float tanh_fast(float x) {
  x = fminf(15.f, fmaxf(-15.f, x));
  float e = exp2f(x * 2.8853900817779268f);  // exp(2x)
  return (e - 1.f) * __builtin_amdgcn_rcpf(e + 1.f);
}
static __device__ __forceinline__ float fast_log(float x) {
  return __builtin_amdgcn_logf(x) * 0.69314718056f;
}
static __device__ __forceinline__ float bf_lo(unsigned int w) {
  return __builtin_bit_cast(float, w << 16);
}
static __device__ __forceinline__ float bf_hi(unsigned int w) {
  return __builtin_bit_cast(float, w & 0xFFFF0000u);
}
static __device__ __forceinline__ f32x4 fzero() {
  f32x4 z; z.x = 0.f; z.y = 0.f; z.z = 0.f; z.w = 0.f; return z;
}

// ---------- pack A-side (rows x K, row-major): frag b=(rfg*nks+ks): lane l holds
// A[rfg*16 + (l&15)][ks*32 + (l>>4)*8 + j], j=0..7 as bf16 pairs (lds-free)
__global__ void pack_a_kernel(const float* __restrict__ A, int M, int Kdim, int nks,
                              unsigned short* __restrict__ dst) {
  int b = blockIdx.x, l = threadIdx.x;
  int rfg = b / nks, ks = b % nks;
  int row = rfg * 16 + (l & 15);
  int k0 = ks * 32 + (l >> 4) * 8;
  f32x4 v0 = fzero(), v1 = fzero();
  if (row < M) {
    const float* p = A + (size_t)row * Kdim + k0;
    if (k0 + 8 <= Kdim) {
      v0 = *reinterpret_cast<const f32x4*>(p);
      v1 = *reinterpret_cast<const f32x4*>(p + 4);
    } else {
      float t[8];
#pragma unroll
      for (int i = 0; i < 8; ++i) t[i] = (k0 + i < Kdim) ? p[i] : 0.f;
      v0.x = t[0]; v0.y = t[1]; v0.z = t[2]; v0.w = t[3];
      v1.x = t[4]; v1.y = t[5]; v1.z = t[6]; v1.w = t[7];
    }
  }
  i32x4 o;
  o.x = (int)cvt_pk_bf16(v0.x, v0.y);
  o.y = (int)cvt_pk_bf16(v0.z, v0.w);
  o.z = (int)cvt_pk_bf16(v1.x, v1.y);
  o.w = (int)cvt_pk_bf16(v1.z, v1.w);
  *reinterpret_cast<i32x4*>(dst + (size_t)b * 512 + l * 8) = o;
}

// ---------- pack W [Kdim][N] row-major -> bf16 frags: lane l holds
// W[ks*32+(l>>4)*8+j][sl*16+(l&15)]
__global__ void pack_b_kernel(const float* __restrict__ W, int Kdim, int N, int nks,
                              unsigned short* __restrict__ dst) {
  int b = blockIdx.x, l = threadIdx.x;
  int sl = b / nks, ks = b % nks;
  int n = sl * 16 + (l & 15);
  int k0 = ks * 32 + (l >> 4) * 8;
  float t[8];
#pragma unroll
  for (int i = 0; i < 8; ++i) {
    int k = k0 + i;
    t[i] = (k < Kdim) ? W[(size_t)k * N + n] : 0.f;
  }
  i32x4 o;
  o.x = (int)cvt_pk_bf16(t[0], t[1]);
  o.y = (int)cvt_pk_bf16(t[2], t[3]);
  o.z = (int)cvt_pk_bf16(t[4], t[5]);
  o.w = (int)cvt_pk_bf16(t[6], t[7]);
  *reinterpret_cast<i32x4*>(dst + (size_t)b * 512 + l * 8) = o;
}

// ---------- pack W -> fp8 frags (512B each) ----------
__global__ void pack_b_fp8_kernel(const float* __restrict__ W, int Kdim, int N, int nks,
                                  unsigned char* __restrict__ dst) {
  int b = blockIdx.x, l = threadIdx.x;
  int sl = b / nks, ks = b % nks;
  int n = sl * 16 + (l & 15);
  int k0 = ks * 32 + (l >> 4) * 8;
  float t[8];
#pragma unroll
  for (int i = 0; i < 8; ++i) {
    int k = k0 + i;
    t[i] = (k < Kdim) ? W[(size_t)k * N + n] : 0.f;
  }
  u32x2 o;
  o.x = pk_fp8x4(t[0], t[1], t[2], t[3]);
  o.y = pk_fp8x4(t[4], t[5], t[6], t[7]);
  *reinterpret_cast<u32x2*>(dst + (size_t)b * 512 + l * 8) = o;
}

// ---------- tb kernel: Etb(bf16) = exp(rho @ alphas), colsum over vocab ----------
// Transposed operands: A = alpha strip (topic cols), B = rho rows.
__global__ __launch_bounds__(512) void tb_kernel(
    const unsigned short* __restrict__ rhop, const unsigned short* __restrict__ alphap,
    unsigned short* __restrict__ Etb, float* __restrict__ colsum) {
  int tid = threadIdx.x;
  int wid = tid >> 6, l = tid & 63;
  int srow = l & 15, q = l >> 4;
  int tile = blockIdx.x;
  const i32x4* rp = reinterpret_cast<const i32x4*>(rhop);
  const i32x4* ap = reinterpret_cast<const i32x4*>(alphap);
  f32x4 acc[4];
#pragma unroll
  for (int rf = 0; rf < 4; ++rf) acc[rf] = fzero();
  for (int ks = 0; ks < 10; ++ks) {
    i32x4 aw = ap[((size_t)wid * 10 + ks) * 64 + l];
#pragma unroll
    for (int rf = 0; rf < 4; ++rf) {
      i32x4 rv = rp[(((size_t)tile * 4 + rf) * 10 + ks) * 64 + l];
      acc[rf] = mfma_bf16(aw, rv, acc[rf]);
    }
  }
  float cs[4] = {0.f, 0.f, 0.f, 0.f};
#pragma unroll
  for (int rf = 0; rf < 4; ++rf) {
    int row = tile * 64 + rf * 16 + srow;
    float e0 = exp2f(acc[rf][0] * LOG2E);
    float e1 = exp2f(acc[rf][1] * LOG2E);
    float e2 = exp2f(acc[rf][2] * LOG2E);
    float e3 = exp2f(acc[rf][3] * LOG2E);
    if (row < V_) {
      u32x2 o;
      o.x = cvt_pk_bf16(e0, e1);
      o.y = cvt_pk_bf16(e2, e3);
      *reinterpret_cast<u32x2*>(Etb + (size_t)row * 128 + wid * 16 + q * 4) = o;
      cs[0] += e0; cs[1] += e1; cs[2] += e2; cs[3] += e3;
    }
  }
#pragma unroll
  for (int d = 1; d < 16; d <<= 1) {
#pragma unroll
    for (int r = 0; r < 4; ++r) cs[r] += __shfl_xor(cs[r], d);
  }
  if (srow == 0) {
#pragma unroll
    for (int r = 0; r < 4; ++r) atomicAdd(&colsum[wid * 16 + q * 4 + r], cs[r]);
  }
}

// ---------- fused main kernel: 64 rows/block, 8 waves, 2 blocks/CU ----------
__global__ __launch_bounds__(512, 4) void fused_kernel(
    const int* __restrict__ bi_idx, const float* __restrict__ biterms,
    const float* __restrict__ q1b, const float* __restrict__ q2b,
    const float* __restrict__ mub, const float* __restrict__ lsb,
    const unsigned short* __restrict__ q1p, const unsigned char* __restrict__ q2p8,
    const unsigned char* __restrict__ headp8,
    const unsigned short* __restrict__ Etb, const float* __restrict__ colsum,
    float* __restrict__ partial) {
  __shared__ __align__(16) unsigned char sH[64 * 824];   // 52,736 B (fp8 h1/h2)
  __shared__ __align__(16) unsigned short sMu[64 * 140]; // 17,920 B (bf16 mu)
  __shared__ float sInv[128];
  __shared__ float sRed[16];

  const int tid = threadIdx.x, wid = tid >> 6, l = tid & 63;
  const int srow = l & 15, q = l >> 4;
  const int row0 = blockIdx.x * 64;

  if (tid < 128) { float c = colsum[tid]; sInv[tid] = 1.f / (c * c); }

  const i32x4* q1pv = reinterpret_cast<const i32x4*>(q1p);
  const float* btbase = biterms + (size_t)(row0 + srow) * 300 + q * 8;
  char* sHb = reinterpret_cast<char*>(sH);

  // ---- GEMM1: h1 = tanh(biterms @ q1 + b1) -> sH fp8 (transposed operands) ----
  auto gemm1 = [&](int sbase, int ns) {
    f32x4 acc1[3][4];
#pragma unroll
    for (int cs = 0; cs < 3; ++cs)
#pragma unroll
      for (int rf = 0; rf < 4; ++rf) acc1[cs][rf] = fzero();
#pragma unroll
    for (int ks = 0; ks < 10; ++ks) {
      i32x4 xf[4];
#pragma unroll
      for (int rf = 0; rf < 4; ++rf) {
        const float* p = btbase + rf * 4800 + ks * 32;
        f32x4 v0 = fzero(), v1 = fzero();
        if (ks < 9) {
          v0 = *reinterpret_cast<const f32x4*>(p);
          v1 = *reinterpret_cast<const f32x4*>(p + 4);
        } else {
          if (q < 2)  v0 = *reinterpret_cast<const f32x4*>(p);
          if (q == 0) v1 = *reinterpret_cast<const f32x4*>(p + 4);
        }
        i32x4 x;
        x.x = (int)cvt_pk_bf16(v0.x, v0.y);
        x.y = (int)cvt_pk_bf16(v0.z, v0.w);
        x.z = (int)cvt_pk_bf16(v1.x, v1.y);
        x.w = (int)cvt_pk_bf16(v1.z, v1.w);
        xf[rf] = x;
      }
#pragma unroll
      for (int cs = 0; cs < 3; ++cs) {
        if (cs < ns) {
          i32x4 w = q1pv[((size_t)(sbase + cs) * 10 + ks) * 64 + l];
#pragma unroll
          for (int rf = 0; rf < 4; ++rf) acc1[cs][rf] = mfma_bf16(w, xf[rf], acc1[cs][rf]);
        }
      }
    }
    for (int cs = 0; cs < ns; ++cs) {
      int s = sbase + cs;
      f32x4 b4 = *reinterpret_cast<const f32x4*>(q1b + s * 16 + q * 4);
#pragma unroll
      for (int rf = 0; rf < 4; ++rf) {
        unsigned int w = pk_fp8x4(tanh_fast(acc1[cs][rf][0] + b4.x),
                                  tanh_fast(acc1[cs][rf][1] + b4.y),
                                  tanh_fast(acc1[cs][rf][2] + b4.z),
                                  tanh_fast(acc1[cs][rf][3] + b4.w));
        *reinterpret_cast<unsigned int*>(sHb + (rf * 16 + srow) * 824 + s * 16 + q * 4) = w;
      }
    }
  };
  gemm1(wid * 3, 3);
  gemm1(24 + wid * 3, 3);
  if (wid < 2) gemm1(48 + wid, 1);
  __syncthreads();

  // ---- GEMM2: h2 = tanh(h1 @ q2 + b2), fp8, in-place sH ----
  f32x4 acc2[7][4];
#pragma unroll
  for (int si = 0; si < 7; ++si)
#pragma unroll
    for (int rf = 0; rf < 4; ++rf) acc2[si][rf] = fzero();
#pragma unroll 5
  for (int ks = 0; ks < 25; ++ks) {
    long a8[4];
#pragma unroll
    for (int rf = 0; rf < 4; ++rf)
      a8[rf] = *reinterpret_cast<const long*>(sHb + (rf * 16 + srow) * 824 + ks * 32 + q * 8);
#pragma unroll
    for (int si = 0; si < 7; ++si) {
      int s = wid + 8 * si;
      if (s < 50) {
        long w = *reinterpret_cast<const long*>(q2p8 + (((size_t)s * 25 + ks) << 9) + (l << 3));
#pragma unroll
        for (int rf = 0; rf < 4; ++rf) acc2[si][rf] = mfma_fp8(w, a8[rf], acc2[si][rf]);
      }
    }
  }
  __syncthreads();  // all reads of h1 done
#pragma unroll
  for (int si = 0; si < 7; ++si) {
    int s = wid + 8 * si;
    if (s < 50) {
      f32x4 b4 = *reinterpret_cast<const f32x4*>(q2b + s * 16 + q * 4);
#pragma unroll
      for (int rf = 0; rf < 4; ++rf) {
        unsigned int w = pk_fp8x4(tanh_fast(acc2[si][rf][0] + b4.x),
                                  tanh_fast(acc2[si][rf][1] + b4.y),
                                  tanh_fast(acc2[si][rf][2] + b4.z),
                                  tanh_fast(acc2[si][rf][3] + b4.w));
        *reinterpret_cast<unsigned int*>(sHb + (rf * 16 + srow) * 824 + s * 16 + q * 4) = w;
      }
    }
  }
  __syncthreads();

  // ---- GEMM3: mu (strip wid), logsigma (strip wid+8); kld; mu -> sMu bf16 ----
  f32x4 acc3[2][4];
#pragma unroll
  for (int t = 0; t < 2; ++t)
#pragma unroll
    for (int rf = 0; rf < 4; ++rf) acc3[t][rf] = fzero();
#pragma unroll 5
  for (int ks = 0; ks < 25; ++ks) {
    long a8[4];
#pragma unroll
    for (int rf = 0; rf < 4; ++rf)
      a8[rf] = *reinterpret_cast<const long*>(sHb + (rf * 16 + srow) * 824 + ks * 32 + q * 8);
    long w0 = *reinterpret_cast<const long*>(headp8 + (((size_t)wid * 25 + ks) << 9) + (l << 3));
    long w1 = *reinterpret_cast<const long*>(headp8 + (((size_t)(wid + 8) * 25 + ks) << 9) + (l << 3));
#pragma unroll
    for (int rf = 0; rf < 4; ++rf) {
      acc3[0][rf] = mfma_fp8(w0, a8[rf], acc3[0][rf]);
      acc3[1][rf] = mfma_fp8(w1, a8[rf], acc3[1][rf]);
    }
  }
  {
    f32x4 mb4 = *reinterpret_cast<const f32x4*>(mub + wid * 16 + q * 4);
    f32x4 lb4 = *reinterpret_cast<const f32x4*>(lsb + wid * 16 + q * 4);
    float kldp = 0.f;
#pragma unroll
    for (int rf = 0; rf < 4; ++rf) {
      float m0 = acc3[0][rf][0] + mb4.x, m1 = acc3[0][rf][1] + mb4.y;
      float m2 = acc3[0][rf][2] + mb4.z, m3 = acc3[0][rf][3] + mb4.w;
      kldp -= m0 * m0 + m1 * m1 + m2 * m2 + m3 * m3;
      u32x2 o;
      o.x = cvt_pk_bf16(m0, m1);
      o.y = cvt_pk_bf16(m2, m3);
      *reinterpret_cast<u32x2*>(reinterpret_cast<char*>(sMu) +
                                (rf * 16 + srow) * 280 + (wid * 16 + q * 4) * 2) = o;
      float v0 = acc3[1][rf][0] + lb4.x, v1 = acc3[1][rf][1] + lb4.y;
      float v2 = acc3[1][rf][2] + lb4.z, v3 = acc3[1][rf][3] + lb4.w;
      kldp += 4.f + v0 + v1 + v2 + v3
            - exp2f(v0 * LOG2E) - exp2f(v1 * LOG2E)
            - exp2f(v2 * LOG2E) - exp2f(v3 * LOG2E);
    }
#pragma unroll
    for (int d = 1; d < 64; d <<= 1) kldp += __shfl_xor(kldp, d);
    if (l == 0) sRed[wid] = kldp;
  }
  __syncthreads();

  // ---- decode: softmax (no max shift) + gather dot ----
  const int2* bi2 = reinterpret_cast<const int2*>(bi_idx);
  const char* sMub = reinterpret_cast<const char*>(sMu);
  f32x2 iv = *reinterpret_cast<const f32x2*>(sInv + 2 * l);
  float lsum = 0.f;
  for (int rr = 0; rr < 8; ++rr) {
    int r = wid * 8 + rr;
    int2 bi = bi2[row0 + r];
    unsigned int mw = *reinterpret_cast<const unsigned int*>(sMub + r * 280 + l * 4);
    float t0 = exp2f(bf_lo(mw) * LOG2E);
    float t1 = exp2f(bf_hi(mw) * LOG2E);
    float den = t0 + t1;
    unsigned int e0w = *reinterpret_cast<const unsigned int*>(
        reinterpret_cast<const char*>(Etb) + (size_t)bi.x * 256 + l * 4);
    unsigned int e1w = *reinterpret_cast<const unsigned int*>(
        reinterpret_cast<const char*>(Etb) + (size_t)bi.y * 256 + l * 4);
    float p = t0 * t0 * bf_lo(e0w) * bf_lo(e1w) * iv.x
            + t1 * t1 * bf_hi(e0w) * bf_hi(e1w) * iv.y;
#pragma unroll
    for (int d = 1; d < 64; d <<= 1) {
      den += __shfl_xor(den, d);
      p   += __shfl_xor(p, d);
    }
    lsum += fast_log(p / (den * den) + 1e-6f);
  }
  if (l == 0) sRed[8 + wid] = lsum;
  __syncthreads();
  if (tid == 0) {
    float k = 0.f, s = 0.f;
#pragma unroll
    for (int i = 0; i < 8; ++i) { k += sRed[i]; s += sRed[8 + i]; }
    atomicAdd(&partial[1], k);
    atomicAdd(&partial[0], s);
  }
}

__global__ void finalize_kernel(const float* __restrict__ partial, float* __restrict__ out) {
  if (threadIdx.x == 0) {
    out[0] = partial[0] / (float)B_;
    out[1] = -0.5f * partial[1] / (float)B_;
  }
}

extern "C" void kernel_launch(void* const* d_in, const int* in_sizes, int n_in,
                              void* d_out, int out_size, void* d_ws, size_t ws_size,
                              hipStream_t stream) {
  const int*   bi_idx   = (const int*)d_in[0];
  const float* biterms  = (const float*)d_in[1];
  const float* rho      = (const float*)d_in[2];
  const float* alphas_W = (const float*)d_in[3];
  const float* q1_W     = (const float*)d_in[4];
  const float* q1_b     = (const float*)d_in[5];
  const float* q2_W     = (const float*)d_in[6];
  const float* q2_b     = (const float*)d_in[7];
  const float* mu_W     = (const float*)d_in[8];
  const float* mu_b     = (const float*)d_in[9];
  const float* ls_W     = (const float*)d_in[10];
  const float* ls_b     = (const float*)d_in[11];

  char* ws = (char*)d_ws;
  unsigned short* Etb   = (unsigned short*)(ws + OFF_ETB);
  float* colsum  = (float*)(ws + OFF_COLSUM);
  float* partial = (float*)(ws + OFF_PART);
  unsigned short* rhop  = (unsigned short*)(ws + OFF_RHOP);
  unsigned short* q1p   = (unsigned short*)(ws + OFF_Q1P);
  unsigned char*  q2p8  = (unsigned char*)(ws + OFF_Q2P8);
  unsigned char*  headp8= (unsigned char*)(ws + OFF_HEADP8);
  unsigned short* alphap= (unsigned short*)(ws + OFF_ALP);

  hipMemsetAsync(ws + OFF_COLSUM, 0, 1024, stream);  // colsum + partials

  pack_a_kernel<<<3128 * 10, 64, 0, stream>>>(rho, V_, E_, 10, rhop);
  pack_b_kernel<<<8 * 10, 64, 0, stream>>>(alphas_W, E_, K_, 10, alphap);
  pack_b_kernel<<<50 * 10, 64, 0, stream>>>(q1_W, E_, H_, 10, q1p);
  pack_b_fp8_kernel<<<50 * 25, 64, 0, stream>>>(q2_W, H_, H_, 25, q2p8);
  pack_b_fp8_kernel<<<8 * 25, 64, 0, stream>>>(mu_W, H_, K_, 25, headp8);
  pack_b_fp8_kernel<<<8 * 25, 64, 0, stream>>>(ls_W, H_, K_, 25, headp8 + (size_t)200 * 512);

  tb_kernel<<<782, 512, 0, stream>>>(rhop, alphap, Etb, colsum);

  fused_kernel<<<B_ / 64, 512, 0, stream>>>(bi_idx, biterms, q1_b, q2_b, mu_b, ls_b,
                                            q1p, q2p8, headp8, Etb, colsum, partial);

  finalize_kernel<<<1, 64, 0, stream>>>(partial, (float*)d_out);
}

// Round 3
// 572.161 us; speedup vs baseline: 1.3620x; 1.3620x over previous
//
#include <hip/hip_runtime.h>
#include <hip/hip_bf16.h>

// Problem dims
#define V_ 50000
#define E_ 300
#define H_ 800
#define K_ 128
#define B_ 131072

typedef float  f32x4 __attribute__((ext_vector_type(4)));
typedef float  f32x2 __attribute__((ext_vector_type(2)));
typedef int    i32x4 __attribute__((ext_vector_type(4)));
typedef unsigned int u32x2 __attribute__((ext_vector_type(2)));
typedef __bf16 bf16x8 __attribute__((ext_vector_type(8)));

#define LOG2E 1.4426950408889634f

// ---------------- ws layout (bytes) ----------------
static constexpr size_t OFF_ETB    = 0;                                  // bf16 [50048][128]
static constexpr size_t SZ_ETB     = (size_t)50048 * 128 * 2;            // 12,812,288
static constexpr size_t OFF_COLSUM = SZ_ETB;                             // 128 f32
static constexpr size_t OFF_PART   = OFF_COLSUM + 512;                   // partial[0]=loss, [1]=kld
static constexpr size_t OFF_Q1P    = OFF_COLSUM + 1024;                  // 50x10 bf16 frags (1KB each)
static constexpr size_t OFF_Q2P8   = OFF_Q1P + (size_t)500 * 1024;       // 50x25 fp8 frags (512B each)
static constexpr size_t OFF_HEADP8 = OFF_Q2P8 + (size_t)1250 * 512;      // 16x25 fp8 frags (mu 0-7, ls 8-15)
static constexpr size_t OFF_ALP    = OFF_HEADP8 + (size_t)400 * 512;     // 8x10 bf16 frags

static __device__ __forceinline__ f32x4 mfma_bf16(i32x4 a, i32x4 b, f32x4 c) {
  return __builtin_amdgcn_mfma_f32_16x16x32_bf16(
      __builtin_bit_cast(bf16x8, a), __builtin_bit_cast(bf16x8, b), c, 0, 0, 0);
}
static __device__ __forceinline__ f32x4 mfma_fp8(long a, long b, f32x4 c) {
  return __builtin_amdgcn_mfma_f32_16x16x32_fp8_fp8(a, b, c, 0, 0, 0);
}

static __device__ __forceinline__ unsigned int cvt_pk_bf16(float a, float b) {
  unsigned int d;
  asm volatile("v_cvt_pk_bf16_f32 %0, %1, %2" : "=v"(d) : "v"(a), "v"(b));
  return d;
}
static __device__ __forceinline__ unsigned int pk_fp8x4(float a, float b, float c, float d) {
  int w = __builtin_amdgcn_cvt_pk_fp8_f32(a, b, 0, false);
  w = __builtin_amdgcn_cvt_pk_fp8_f32(c, d, w, true);
  return (unsigned int)w;
}

static __device__ __forceinline__ float tanh_fast(float x) {
  x = fminf(15.f, fmaxf(-15.f, x));
  float e = exp2f(x * 2.8853900817779268f);  // exp(2x)
  return (e - 1.f) * __builtin_amdgcn_rcpf(e + 1.f);
}
static __device__ __forceinline__ float fast_log(float x) {
  return __builtin_amdgcn_logf(x) * 0.69314718056f;
}
static __device__ __forceinline__ float bf_lo(unsigned int w) {
  return __builtin_bit_cast(float, w << 16);
}
static __device__ __forceinline__ float bf_hi(unsigned int w) {
  return __builtin_bit_cast(float, w & 0xFFFF0000u);
}
static __device__ __forceinline__ f32x4 fzero() {
  f32x4 z; z.x = 0.f; z.y = 0.f; z.z = 0.f; z.w = 0.f; return z;
}

// ---------- pack W [Kdim][N] row-major -> bf16 frags: lane l holds
// W[ks*32+(l>>4)*8+j][sl*16+(l&15)]
__global__ void pack_b_kernel(const float* __restrict__ W, int Kdim, int N, int nks,
                              unsigned short* __restrict__ dst) {
  int b = blockIdx.x, l = threadIdx.x;
  int sl = b / nks, ks = b % nks;
  int n = sl * 16 + (l & 15);
  int k0 = ks * 32 + (l >> 4) * 8;
  float t[8];
#pragma unroll
  for (int i = 0; i < 8; ++i) {
    int k = k0 + i;
    t[i] = (k < Kdim) ? W[(size_t)k * N + n] : 0.f;
  }
  i32x4 o;
  o.x = (int)cvt_pk_bf16(t[0], t[1]);
  o.y = (int)cvt_pk_bf16(t[2], t[3]);
  o.z = (int)cvt_pk_bf16(t[4], t[5]);
  o.w = (int)cvt_pk_bf16(t[6], t[7]);
  *reinterpret_cast<i32x4*>(dst + (size_t)b * 512 + l * 8) = o;
}

// ---------- pack W -> fp8 frags (512B each) ----------
__global__ void pack_b_fp8_kernel(const float* __restrict__ W, int Kdim, int N, int nks,
                                  unsigned char* __restrict__ dst) {
  int b = blockIdx.x, l = threadIdx.x;
  int sl = b / nks, ks = b % nks;
  int n = sl * 16 + (l & 15);
  int k0 = ks * 32 + (l >> 4) * 8;
  float t[8];
#pragma unroll
  for (int i = 0; i < 8; ++i) {
    int k = k0 + i;
    t[i] = (k < Kdim) ? W[(size_t)k * N + n] : 0.f;
  }
  u32x2 o;
  o.x = pk_fp8x4(t[0], t[1], t[2], t[3]);
  o.y = pk_fp8x4(t[4], t[5], t[6], t[7]);
  *reinterpret_cast<u32x2*>(dst + (size_t)b * 512 + l * 8) = o;
}

// ---------- tb kernel: Etb(bf16) = exp(rho @ alphas), colsum over vocab ----------
// A = alpha strip (16 topics), B = rho rows read DIRECTLY from f32 global.
__global__ __launch_bounds__(512) void tb_kernel(
    const float* __restrict__ rho, const unsigned short* __restrict__ alphap,
    unsigned short* __restrict__ Etb, float* __restrict__ colsum) {
  int tid = threadIdx.x;
  int wid = tid >> 6, l = tid & 63;
  int srow = l & 15, q = l >> 4;
  int tile = blockIdx.x;
  const i32x4* ap = reinterpret_cast<const i32x4*>(alphap);
  f32x4 acc[4];
#pragma unroll
  for (int rf = 0; rf < 4; ++rf) acc[rf] = fzero();
  for (int ks = 0; ks < 10; ++ks) {
    i32x4 aw = ap[((size_t)wid * 10 + ks) * 64 + l];
#pragma unroll
    for (int rf = 0; rf < 4; ++rf) {
      int row = tile * 64 + rf * 16 + srow;
      f32x4 v0 = fzero(), v1 = fzero();
      if (row < V_) {
        const float* p = rho + (size_t)row * 300 + ks * 32 + q * 8;
        if (ks < 9) {
          v0 = *reinterpret_cast<const f32x4*>(p);
          v1 = *reinterpret_cast<const f32x4*>(p + 4);
        } else {
          if (q < 2)  v0 = *reinterpret_cast<const f32x4*>(p);
          if (q == 0) v1 = *reinterpret_cast<const f32x4*>(p + 4);
        }
      }
      i32x4 rv;
      rv.x = (int)cvt_pk_bf16(v0.x, v0.y);
      rv.y = (int)cvt_pk_bf16(v0.z, v0.w);
      rv.z = (int)cvt_pk_bf16(v1.x, v1.y);
      rv.w = (int)cvt_pk_bf16(v1.z, v1.w);
      acc[rf] = mfma_bf16(aw, rv, acc[rf]);
    }
  }
  float cs[4] = {0.f, 0.f, 0.f, 0.f};
#pragma unroll
  for (int rf = 0; rf < 4; ++rf) {
    int row = tile * 64 + rf * 16 + srow;
    float e0 = exp2f(acc[rf][0] * LOG2E);
    float e1 = exp2f(acc[rf][1] * LOG2E);
    float e2 = exp2f(acc[rf][2] * LOG2E);
    float e3 = exp2f(acc[rf][3] * LOG2E);
    if (row < V_) {
      u32x2 o;
      o.x = cvt_pk_bf16(e0, e1);
      o.y = cvt_pk_bf16(e2, e3);
      *reinterpret_cast<u32x2*>(Etb + (size_t)row * 128 + wid * 16 + q * 4) = o;
      cs[0] += e0; cs[1] += e1; cs[2] += e2; cs[3] += e3;
    }
  }
#pragma unroll
  for (int d = 1; d < 16; d <<= 1) {
#pragma unroll
    for (int r = 0; r < 4; ++r) cs[r] += __shfl_xor(cs[r], d);
  }
  if (srow == 0) {
#pragma unroll
    for (int r = 0; r < 4; ++r) atomicAdd(&colsum[wid * 16 + q * 4 + r], cs[r]);
  }
}

// ---------- fused main kernel: 64 rows/block, 8 waves, target 2 blocks/CU ----------
// launch_bounds 2nd arg = min BLOCKS/CU (CUDA semantics, verified r1/r2):
// 2 blocks x 8 waves / 4 SIMD = 4 waves/EU -> 128 VGPR cap. Row-split passes keep
// accumulator peak at 56 f32 so 128 suffices without spill.
__global__ __launch_bounds__(512, 2) void fused_kernel(
    const int* __restrict__ bi_idx, const float* __restrict__ biterms,
    const float* __restrict__ q1b, const float* __restrict__ q2b,
    const float* __restrict__ mub, const float* __restrict__ lsb,
    const unsigned short* __restrict__ q1p, const unsigned char* __restrict__ q2p8,
    const unsigned char* __restrict__ headp8,
    const unsigned short* __restrict__ Etb, const float* __restrict__ colsum,
    float* __restrict__ partial) {
  __shared__ __align__(16) unsigned char sH[64 * 824];   // 52,736 B (fp8 h1/h2)
  __shared__ __align__(16) unsigned short sMu[64 * 140]; // 17,920 B (bf16 mu)
  __shared__ float sInv[128];
  __shared__ float sRed[16];

  const int tid = threadIdx.x, wid = tid >> 6, l = tid & 63;
  const int srow = l & 15, q = l >> 4;
  const int row0 = blockIdx.x * 64;

  if (tid < 128) { float c = colsum[tid]; sInv[tid] = 1.f / (c * c); }

  const i32x4* q1pv = reinterpret_cast<const i32x4*>(q1p);
  char* sHb = reinterpret_cast<char*>(sH);

  // ---- GEMM1: h1 = tanh(biterms @ q1 + b1) -> sH fp8; two 32-row passes ----
  auto gemm1_pass = [&](int p) {
    f32x4 acc1[7][2];
#pragma unroll
    for (int si = 0; si < 7; ++si) {
      acc1[si][0] = fzero(); acc1[si][1] = fzero();
    }
    for (int ks = 0; ks < 10; ++ks) {
      i32x4 xf[2];
#pragma unroll
      for (int rl = 0; rl < 2; ++rl) {
        const float* ptr = biterms + (size_t)(row0 + (2 * p + rl) * 16 + srow) * 300 + ks * 32 + q * 8;
        f32x4 v0 = fzero(), v1 = fzero();
        if (ks < 9) {
          v0 = *reinterpret_cast<const f32x4*>(ptr);
          v1 = *reinterpret_cast<const f32x4*>(ptr + 4);
        } else {
          if (q < 2)  v0 = *reinterpret_cast<const f32x4*>(ptr);
          if (q == 0) v1 = *reinterpret_cast<const f32x4*>(ptr + 4);
        }
        i32x4 x;
        x.x = (int)cvt_pk_bf16(v0.x, v0.y);
        x.y = (int)cvt_pk_bf16(v0.z, v0.w);
        x.z = (int)cvt_pk_bf16(v1.x, v1.y);
        x.w = (int)cvt_pk_bf16(v1.z, v1.w);
        xf[rl] = x;
      }
#pragma unroll
      for (int si = 0; si < 7; ++si) {
        int s = wid + 8 * si;
        if (s < 50) {
          i32x4 w = q1pv[((size_t)s * 10 + ks) * 64 + l];
          acc1[si][0] = mfma_bf16(w, xf[0], acc1[si][0]);
          acc1[si][1] = mfma_bf16(w, xf[1], acc1[si][1]);
        }
      }
    }
#pragma unroll
    for (int si = 0; si < 7; ++si) {
      int s = wid + 8 * si;
      if (s < 50) {
        f32x4 b4 = *reinterpret_cast<const f32x4*>(q1b + s * 16 + q * 4);
#pragma unroll
        for (int rl = 0; rl < 2; ++rl) {
          unsigned int w = pk_fp8x4(tanh_fast(acc1[si][rl][0] + b4.x),
                                    tanh_fast(acc1[si][rl][1] + b4.y),
                                    tanh_fast(acc1[si][rl][2] + b4.z),
                                    tanh_fast(acc1[si][rl][3] + b4.w));
          *reinterpret_cast<unsigned int*>(
              sHb + ((2 * p + rl) * 16 + srow) * 824 + s * 16 + q * 4) = w;
        }
      }
    }
  };
  gemm1_pass(0);
  gemm1_pass(1);
  __syncthreads();

  // ---- GEMM2: h2 = tanh(h1 @ q2 + b2), fp8, in-place over sH; two 32-row passes ----
  f32x4 acc2[7][2];
  auto gemm2_read = [&](int p) {
#pragma unroll
    for (int si = 0; si < 7; ++si) {
      acc2[si][0] = fzero(); acc2[si][1] = fzero();
    }
    for (int ks = 0; ks < 25; ++ks) {
      long a0 = *reinterpret_cast<const long*>(sHb + ((2 * p + 0) * 16 + srow) * 824 + ks * 32 + q * 8);
      long a1 = *reinterpret_cast<const long*>(sHb + ((2 * p + 1) * 16 + srow) * 824 + ks * 32 + q * 8);
#pragma unroll
      for (int si = 0; si < 7; ++si) {
        int s = wid + 8 * si;
        if (s < 50) {
          long w = *reinterpret_cast<const long*>(q2p8 + (((size_t)s * 25 + ks) << 9) + (l << 3));
          acc2[si][0] = mfma_fp8(w, a0, acc2[si][0]);
          acc2[si][1] = mfma_fp8(w, a1, acc2[si][1]);
        }
      }
    }
  };
  auto gemm2_write = [&](int p) {
#pragma unroll
    for (int si = 0; si < 7; ++si) {
      int s = wid + 8 * si;
      if (s < 50) {
        f32x4 b4 = *reinterpret_cast<const f32x4*>(q2b + s * 16 + q * 4);
#pragma unroll
        for (int rl = 0; rl < 2; ++rl) {
          unsigned int w = pk_fp8x4(tanh_fast(acc2[si][rl][0] + b4.x),
                                    tanh_fast(acc2[si][rl][1] + b4.y),
                                    tanh_fast(acc2[si][rl][2] + b4.z),
                                    tanh_fast(acc2[si][rl][3] + b4.w));
          *reinterpret_cast<unsigned int*>(
              sHb + ((2 * p + rl) * 16 + srow) * 824 + s * 16 + q * 4) = w;
        }
      }
    }
  };
  gemm2_read(0);
  __syncthreads();          // all pass-0 reads of h1 rows 0-31 done
  gemm2_write(0);           // writes rows 0-31 (disjoint from pass-1 reads below)
  gemm2_read(1);
  __syncthreads();          // all pass-1 reads of h1 rows 32-63 done
  gemm2_write(1);
  __syncthreads();          // h2 complete

  // ---- GEMM3: mu (strip wid), logsigma (strip wid+8); kld; mu -> sMu bf16 ----
  f32x4 acc3[2][4];
#pragma unroll
  for (int t = 0; t < 2; ++t)
#pragma unroll
    for (int rf = 0; rf < 4; ++rf) acc3[t][rf] = fzero();
  for (int ks = 0; ks < 25; ++ks) {
    long a8[4];
#pragma unroll
    for (int rf = 0; rf < 4; ++rf)
      a8[rf] = *reinterpret_cast<const long*>(sHb + (rf * 16 + srow) * 824 + ks * 32 + q * 8);
    long w0 = *reinterpret_cast<const long*>(headp8 + (((size_t)wid * 25 + ks) << 9) + (l << 3));
    long w1 = *reinterpret_cast<const long*>(headp8 + (((size_t)(wid + 8) * 25 + ks) << 9) + (l << 3));
#pragma unroll
    for (int rf = 0; rf < 4; ++rf) {
      acc3[0][rf] = mfma_fp8(w0, a8[rf], acc3[0][rf]);
      acc3[1][rf] = mfma_fp8(w1, a8[rf], acc3[1][rf]);
    }
  }
  {
    f32x4 mb4 = *reinterpret_cast<const f32x4*>(mub + wid * 16 + q * 4);
    f32x4 lb4 = *reinterpret_cast<const f32x4*>(lsb + wid * 16 + q * 4);
    float kldp = 0.f;
#pragma unroll
    for (int rf = 0; rf < 4; ++rf) {
      float m0 = acc3[0][rf][0] + mb4.x, m1 = acc3[0][rf][1] + mb4.y;
      float m2 = acc3[0][rf][2] + mb4.z, m3 = acc3[0][rf][3] + mb4.w;
      kldp -= m0 * m0 + m1 * m1 + m2 * m2 + m3 * m3;
      u32x2 o;
      o.x = cvt_pk_bf16(m0, m1);
      o.y = cvt_pk_bf16(m2, m3);
      *reinterpret_cast<u32x2*>(reinterpret_cast<char*>(sMu) +
                                (rf * 16 + srow) * 280 + (wid * 16 + q * 4) * 2) = o;
      float v0 = acc3[1][rf][0] + lb4.x, v1 = acc3[1][rf][1] + lb4.y;
      float v2 = acc3[1][rf][2] + lb4.z, v3 = acc3[1][rf][3] + lb4.w;
      kldp += 4.f + v0 + v1 + v2 + v3
            - exp2f(v0 * LOG2E) - exp2f(v1 * LOG2E)
            - exp2f(v2 * LOG2E) - exp2f(v3 * LOG2E);
    }
#pragma unroll
    for (int d = 1; d < 64; d <<= 1) kldp += __shfl_xor(kldp, d);
    if (l == 0) sRed[wid] = kldp;
  }
  __syncthreads();

  // ---- decode: softmax (no max shift) + gather dot ----
  const int2* bi2 = reinterpret_cast<const int2*>(bi_idx);
  const char* sMub = reinterpret_cast<const char*>(sMu);
  f32x2 iv = *reinterpret_cast<const f32x2*>(sInv + 2 * l);
  float lsum = 0.f;
  for (int rr = 0; rr < 8; ++rr) {
    int r = wid * 8 + rr;
    int2 bi = bi2[row0 + r];
    unsigned int mw = *reinterpret_cast<const unsigned int*>(sMub + r * 280 + l * 4);
    float t0 = exp2f(bf_lo(mw) * LOG2E);
    float t1 = exp2f(bf_hi(mw) * LOG2E);
    float den = t0 + t1;
    unsigned int e0w = *reinterpret_cast<const unsigned int*>(
        reinterpret_cast<const char*>(Etb) + (size_t)bi.x * 256 + l * 4);
    unsigned int e1w = *reinterpret_cast<const unsigned int*>(
        reinterpret_cast<const char*>(Etb) + (size_t)bi.y * 256 + l * 4);
    float p = t0 * t0 * bf_lo(e0w) * bf_lo(e1w) * iv.x
            + t1 * t1 * bf_hi(e0w) * bf_hi(e1w) * iv.y;
#pragma unroll
    for (int d = 1; d < 64; d <<= 1) {
      den += __shfl_xor(den, d);
      p   += __shfl_xor(p, d);
    }
    lsum += fast_log(p / (den * den) + 1e-6f);
  }
  if (l == 0) sRed[8 + wid] = lsum;
  __syncthreads();
  if (tid == 0) {
    float k = 0.f, s = 0.f;
#pragma unroll
    for (int i = 0; i < 8; ++i) { k += sRed[i]; s += sRed[8 + i]; }
    atomicAdd(&partial[1], k);
    atomicAdd(&partial[0], s);
  }
}

__global__ void finalize_kernel(const float* __restrict__ partial, float* __restrict__ out) {
  if (threadIdx.x == 0) {
    out[0] = partial[0] / (float)B_;
    out[1] = -0.5f * partial[1] / (float)B_;
  }
}

extern "C" void kernel_launch(void* const* d_in, const int* in_sizes, int n_in,
                              void* d_out, int out_size, void* d_ws, size_t ws_size,
                              hipStream_t stream) {
  const int*   bi_idx   = (const int*)d_in[0];
  const float* biterms  = (const float*)d_in[1];
  const float* rho      = (const float*)d_in[2];
  const float* alphas_W = (const float*)d_in[3];
  const float* q1_W     = (const float*)d_in[4];
  const float* q1_b     = (const float*)d_in[5];
  const float* q2_W     = (const float*)d_in[6];
  const float* q2_b     = (const float*)d_in[7];
  const float* mu_W     = (const float*)d_in[8];
  const float* mu_b     = (const float*)d_in[9];
  const float* ls_W     = (const float*)d_in[10];
  const float* ls_b     = (const float*)d_in[11];

  char* ws = (char*)d_ws;
  unsigned short* Etb   = (unsigned short*)(ws + OFF_ETB);
  float* colsum  = (float*)(ws + OFF_COLSUM);
  float* partial = (float*)(ws + OFF_PART);
  unsigned short* q1p   = (unsigned short*)(ws + OFF_Q1P);
  unsigned char*  q2p8  = (unsigned char*)(ws + OFF_Q2P8);
  unsigned char*  headp8= (unsigned char*)(ws + OFF_HEADP8);
  unsigned short* alphap= (unsigned short*)(ws + OFF_ALP);

  hipMemsetAsync(ws + OFF_COLSUM, 0, 1024, stream);  // colsum + partials

  pack_b_kernel<<<8 * 10, 64, 0, stream>>>(alphas_W, E_, K_, 10, alphap);
  pack_b_kernel<<<50 * 10, 64, 0, stream>>>(q1_W, E_, H_, 10, q1p);
  pack_b_fp8_kernel<<<50 * 25, 64, 0, stream>>>(q2_W, H_, H_, 25, q2p8);
  pack_b_fp8_kernel<<<8 * 25, 64, 0, stream>>>(mu_W, H_, K_, 25, headp8);
  pack_b_fp8_kernel<<<8 * 25, 64, 0, stream>>>(ls_W, H_, K_, 25, headp8 + (size_t)200 * 512);

  tb_kernel<<<782, 512, 0, stream>>>(rho, alphap, Etb, colsum);

  fused_kernel<<<B_ / 64, 512, 0, stream>>>(bi_idx, biterms, q1_b, q2_b, mu_b, ls_b,
                                            q1p, q2p8, headp8, Etb, colsum, partial);

  finalize_kernel<<<1, 64, 0, stream>>>(partial, (float*)d_out);
}

// Round 4
// 557.985 us; speedup vs baseline: 1.3966x; 1.0254x over previous
//
#include <hip/hip_runtime.h>
#include <hip/hip_bf16.h>

// Problem dims
#define V_ 50000
#define E_ 300
#define H_ 800
#define K_ 128
#define B_ 131072

typedef float  f32x4 __attribute__((ext_vector_type(4)));
typedef float  f32x2 __attribute__((ext_vector_type(2)));
typedef int    i32x4 __attribute__((ext_vector_type(4)));
typedef unsigned int u32x2 __attribute__((ext_vector_type(2)));
typedef unsigned int u32x4 __attribute__((ext_vector_type(4)));
typedef __bf16 bf16x8 __attribute__((ext_vector_type(8)));

#define LOG2E 1.4426950408889634f

// ---------------- ws layout (bytes) ----------------
static constexpr size_t OFF_ETB    = 0;                                  // bf16 [50048][128]
static constexpr size_t SZ_ETB     = (size_t)50048 * 128 * 2;            // 12,812,288
static constexpr size_t OFF_COLSUM = SZ_ETB;                             // 128 f32
static constexpr size_t OFF_PART   = OFF_COLSUM + 512;                   // partial[0]=loss, [1]=kld
static constexpr size_t OFF_Q1P8   = OFF_COLSUM + 1024;                  // 50x10 fp8 frags (512B)
static constexpr size_t OFF_Q2P8   = OFF_Q1P8 + (size_t)500 * 512;       // 50x25 fp8 frags
static constexpr size_t OFF_HEADP8 = OFF_Q2P8 + (size_t)1250 * 512;      // 16x25 fp8 frags (mu 0-7, ls 8-15)
static constexpr size_t OFF_ALP    = OFF_HEADP8 + (size_t)400 * 512;     // 8x10 bf16 frags (1KB)
static constexpr size_t OFF_XP8    = OFF_ALP + (size_t)80 * 1024;        // 8192 rfg x 10 ks x 512B

static __device__ __forceinline__ f32x4 mfma_bf16(i32x4 a, i32x4 b, f32x4 c) {
  return __builtin_amdgcn_mfma_f32_16x16x32_bf16(
      __builtin_bit_cast(bf16x8, a), __builtin_bit_cast(bf16x8, b), c, 0, 0, 0);
}
static __device__ __forceinline__ f32x4 mfma_fp8(long a, long b, f32x4 c) {
  return __builtin_amdgcn_mfma_f32_16x16x32_fp8_fp8(a, b, c, 0, 0, 0);
}

static __device__ __forceinline__ unsigned int cvt_pk_bf16(float a, float b) {
  unsigned int d;
  asm volatile("v_cvt_pk_bf16_f32 %0, %1, %2" : "=v"(d) : "v"(a), "v"(b));
  return d;
}
static __device__ __forceinline__ unsigned int pk_fp8x4(float a, float b, float c, float d) {
  int w = __builtin_amdgcn_cvt_pk_fp8_f32(a, b, 0, false);
  w = __builtin_amdgcn_cvt_pk_fp8_f32(c, d, w, true);
  return (unsigned int)w;
}

// tanh(x) = 1 - 2/(exp(2x)+1); correct limits at +/-inf without clamping.
static __device__ __forceinline__ float tanh_fast(float x) {
  float e = exp2f(x * 2.8853900817779268f);  // exp(2x)
  return __builtin_fmaf(-2.f, __builtin_amdgcn_rcpf(e + 1.f), 1.f);
}
static __device__ __forceinline__ float fast_log(float x) {
  return __builtin_amdgcn_logf(x) * 0.69314718056f;
}
static __device__ __forceinline__ float bf_lo(unsigned int w) {
  return __builtin_bit_cast(float, w << 16);
}
static __device__ __forceinline__ float bf_hi(unsigned int w) {
  return __builtin_bit_cast(float, w & 0xFFFF0000u);
}
static __device__ __forceinline__ f32x4 fzero() {
  f32x4 z; z.x = 0.f; z.y = 0.f; z.z = 0.f; z.w = 0.f; return z;
}

// ---------- pack biterms -> fp8 x-fragments: frag b=(rfg*10+ks): lane l holds
// X[rfg*16 + (l&15)][ks*32 + (l>>4)*8 + j], j=0..7, zero-padded past 300
__global__ void pack_x_fp8_kernel(const float* __restrict__ X, unsigned char* __restrict__ dst) {
  int b = blockIdx.x, l = threadIdx.x;
  int rfg = b / 10, ks = b - rfg * 10;
  int row = rfg * 16 + (l & 15);
  int k0 = ks * 32 + (l >> 4) * 8;
  const float* p = X + (size_t)row * 300 + k0;
  f32x4 v0 = fzero(), v1 = fzero();
  if (ks < 9) {
    v0 = *reinterpret_cast<const f32x4*>(p);
    v1 = *reinterpret_cast<const f32x4*>(p + 4);
  } else {
    float t[8];
#pragma unroll
    for (int i = 0; i < 8; ++i) t[i] = (k0 + i < 300) ? p[i] : 0.f;
    v0.x = t[0]; v0.y = t[1]; v0.z = t[2]; v0.w = t[3];
    v1.x = t[4]; v1.y = t[5]; v1.z = t[6]; v1.w = t[7];
  }
  u32x2 o;
  o.x = pk_fp8x4(v0.x, v0.y, v0.z, v0.w);
  o.y = pk_fp8x4(v1.x, v1.y, v1.z, v1.w);
  *reinterpret_cast<u32x2*>(dst + (size_t)b * 512 + l * 8) = o;
}

// ---------- pack W [Kdim][N] row-major -> bf16 frags ----------
__global__ void pack_b_kernel(const float* __restrict__ W, int Kdim, int N, int nks,
                              unsigned short* __restrict__ dst) {
  int b = blockIdx.x, l = threadIdx.x;
  int sl = b / nks, ks = b % nks;
  int n = sl * 16 + (l & 15);
  int k0 = ks * 32 + (l >> 4) * 8;
  float t[8];
#pragma unroll
  for (int i = 0; i < 8; ++i) {
    int k = k0 + i;
    t[i] = (k < Kdim) ? W[(size_t)k * N + n] : 0.f;
  }
  i32x4 o;
  o.x = (int)cvt_pk_bf16(t[0], t[1]);
  o.y = (int)cvt_pk_bf16(t[2], t[3]);
  o.z = (int)cvt_pk_bf16(t[4], t[5]);
  o.w = (int)cvt_pk_bf16(t[6], t[7]);
  *reinterpret_cast<i32x4*>(dst + (size_t)b * 512 + l * 8) = o;
}

// ---------- pack W -> fp8 frags (512B each) ----------
__global__ void pack_b_fp8_kernel(const float* __restrict__ W, int Kdim, int N, int nks,
                                  unsigned char* __restrict__ dst) {
  int b = blockIdx.x, l = threadIdx.x;
  int sl = b / nks, ks = b % nks;
  int n = sl * 16 + (l & 15);
  int k0 = ks * 32 + (l >> 4) * 8;
  float t[8];
#pragma unroll
  for (int i = 0; i < 8; ++i) {
    int k = k0 + i;
    t[i] = (k < Kdim) ? W[(size_t)k * N + n] : 0.f;
  }
  u32x2 o;
  o.x = pk_fp8x4(t[0], t[1], t[2], t[3]);
  o.y = pk_fp8x4(t[4], t[5], t[6], t[7]);
  *reinterpret_cast<u32x2*>(dst + (size_t)b * 512 + l * 8) = o;
}

// ---------- tb kernel: Etb(bf16) = exp(rho @ alphas), colsum over vocab ----------
__global__ __launch_bounds__(512) void tb_kernel(
    const float* __restrict__ rho, const unsigned short* __restrict__ alphap,
    unsigned short* __restrict__ Etb, float* __restrict__ colsum) {
  int tid = threadIdx.x;
  int wid = tid >> 6, l = tid & 63;
  int srow = l & 15, q = l >> 4;
  int tile = blockIdx.x;
  const i32x4* ap = reinterpret_cast<const i32x4*>(alphap);
  f32x4 acc[4];
#pragma unroll
  for (int rf = 0; rf < 4; ++rf) acc[rf] = fzero();
  for (int ks = 0; ks < 10; ++ks) {
    i32x4 aw = ap[((size_t)wid * 10 + ks) * 64 + l];
#pragma unroll
    for (int rf = 0; rf < 4; ++rf) {
      int row = tile * 64 + rf * 16 + srow;
      f32x4 v0 = fzero(), v1 = fzero();
      if (row < V_) {
        const float* p = rho + (size_t)row * 300 + ks * 32 + q * 8;
        if (ks < 9) {
          v0 = *reinterpret_cast<const f32x4*>(p);
          v1 = *reinterpret_cast<const f32x4*>(p + 4);
        } else {
          if (q < 2)  v0 = *reinterpret_cast<const f32x4*>(p);
          if (q == 0) v1 = *reinterpret_cast<const f32x4*>(p + 4);
        }
      }
      i32x4 rv;
      rv.x = (int)cvt_pk_bf16(v0.x, v0.y);
      rv.y = (int)cvt_pk_bf16(v0.z, v0.w);
      rv.z = (int)cvt_pk_bf16(v1.x, v1.y);
      rv.w = (int)cvt_pk_bf16(v1.z, v1.w);
      acc[rf] = mfma_bf16(aw, rv, acc[rf]);
    }
  }
  float cs[4] = {0.f, 0.f, 0.f, 0.f};
#pragma unroll
  for (int rf = 0; rf < 4; ++rf) {
    int row = tile * 64 + rf * 16 + srow;
    float e0 = exp2f(acc[rf][0] * LOG2E);
    float e1 = exp2f(acc[rf][1] * LOG2E);
    float e2 = exp2f(acc[rf][2] * LOG2E);
    float e3 = exp2f(acc[rf][3] * LOG2E);
    if (row < V_) {
      u32x2 o;
      o.x = cvt_pk_bf16(e0, e1);
      o.y = cvt_pk_bf16(e2, e3);
      *reinterpret_cast<u32x2*>(Etb + (size_t)row * 128 + wid * 16 + q * 4) = o;
      cs[0] += e0; cs[1] += e1; cs[2] += e2; cs[3] += e3;
    }
  }
#pragma unroll
  for (int d = 1; d < 16; d <<= 1) {
#pragma unroll
    for (int r = 0; r < 4; ++r) cs[r] += __shfl_xor(cs[r], d);
  }
  if (srow == 0) {
#pragma unroll
    for (int r = 0; r < 4; ++r) atomicAdd(&colsum[wid * 16 + q * 4 + r], cs[r]);
  }
}

// ---------- fused main kernel: 64 rows/block, 8 waves, 2 blocks/CU ----------
__global__ __launch_bounds__(512, 2) void fused_kernel(
    const int* __restrict__ bi_idx,
    const float* __restrict__ q1b, const float* __restrict__ q2b,
    const float* __restrict__ mub, const float* __restrict__ lsb,
    const unsigned char* __restrict__ xp8, const unsigned char* __restrict__ q1p8,
    const unsigned char* __restrict__ q2p8, const unsigned char* __restrict__ headp8,
    const unsigned short* __restrict__ Etb, const float* __restrict__ colsum,
    float* __restrict__ partial) {
  __shared__ __align__(16) unsigned char sH[64 * 824];    // 52,736 B (fp8 h1/h2)
  __shared__ __align__(16) unsigned char sMuB[64 * 256];  // 16,384 B (bf16 mu, XOR-swizzled)
  __shared__ __align__(16) float sInv[128];
  __shared__ float sRed[16];

  const int tid = threadIdx.x, wid = tid >> 6, l = tid & 63;
  const int srow = l & 15, q = l >> 4;
  const int row0 = blockIdx.x * 64;

  if (tid < 128) { float c = colsum[tid]; sInv[tid] = 1.f / (c * c); }

  char* sHb = reinterpret_cast<char*>(sH);

  // ---- GEMM1: h1 = tanh(x @ q1 + b1) -> sH fp8; two 32-row passes, fp8 MFMA ----
  const char* wbase1[7];
#pragma unroll
  for (int si = 0; si < 7; ++si) {
    int s = wid + 8 * si;
    wbase1[si] = reinterpret_cast<const char*>(q1p8) + ((size_t)s * 10) * 512 + l * 8;
  }
  auto gemm1_pass = [&](int p) {
    f32x4 acc1[7][2];
#pragma unroll
    for (int si = 0; si < 7; ++si) { acc1[si][0] = fzero(); acc1[si][1] = fzero(); }
    const char* x0p = reinterpret_cast<const char*>(xp8) +
                      ((size_t)(blockIdx.x * 4 + 2 * p) * 10) * 512 + l * 8;
#pragma unroll
    for (int ks = 0; ks < 10; ++ks) {
      long x0 = *reinterpret_cast<const long*>(x0p + ks * 512);
      long x1 = *reinterpret_cast<const long*>(x0p + (10 + ks) * 512);
#pragma unroll
      for (int si = 0; si < 7; ++si) {
        if (wid + 8 * si < 50) {
          long w = *reinterpret_cast<const long*>(wbase1[si] + ks * 512);
          acc1[si][0] = mfma_fp8(w, x0, acc1[si][0]);
          acc1[si][1] = mfma_fp8(w, x1, acc1[si][1]);
        }
      }
    }
#pragma unroll
    for (int si = 0; si < 7; ++si) {
      int s = wid + 8 * si;
      if (s < 50) {
        f32x4 b4 = *reinterpret_cast<const f32x4*>(q1b + s * 16 + q * 4);
#pragma unroll
        for (int rl = 0; rl < 2; ++rl) {
          unsigned int w = pk_fp8x4(tanh_fast(acc1[si][rl][0] + b4.x),
                                    tanh_fast(acc1[si][rl][1] + b4.y),
                                    tanh_fast(acc1[si][rl][2] + b4.z),
                                    tanh_fast(acc1[si][rl][3] + b4.w));
          *reinterpret_cast<unsigned int*>(
              sHb + ((2 * p + rl) * 16 + srow) * 824 + s * 16 + q * 4) = w;
        }
      }
    }
  };
  gemm1_pass(0);
  gemm1_pass(1);
  __syncthreads();

  // ---- GEMM2: h2 = tanh(h1 @ q2 + b2), fp8, in-place over sH; two 32-row passes ----
  const char* wbase2[7];
#pragma unroll
  for (int si = 0; si < 7; ++si) {
    int s = wid + 8 * si;
    wbase2[si] = reinterpret_cast<const char*>(q2p8) + ((size_t)s * 25) * 512 + l * 8;
  }
  f32x4 acc2[7][2];
  auto gemm2_read = [&](int p) {
#pragma unroll
    for (int si = 0; si < 7; ++si) { acc2[si][0] = fzero(); acc2[si][1] = fzero(); }
#pragma unroll 5
    for (int ks = 0; ks < 25; ++ks) {
      long a0 = *reinterpret_cast<const long*>(sHb + ((2 * p + 0) * 16 + srow) * 824 + ks * 32 + q * 8);
      long a1 = *reinterpret_cast<const long*>(sHb + ((2 * p + 1) * 16 + srow) * 824 + ks * 32 + q * 8);
#pragma unroll
      for (int si = 0; si < 7; ++si) {
        if (wid + 8 * si < 50) {
          long w = *reinterpret_cast<const long*>(wbase2[si] + ks * 512);
          acc2[si][0] = mfma_fp8(w, a0, acc2[si][0]);
          acc2[si][1] = mfma_fp8(w, a1, acc2[si][1]);
        }
      }
    }
  };
  auto gemm2_write = [&](int p) {
#pragma unroll
    for (int si = 0; si < 7; ++si) {
      int s = wid + 8 * si;
      if (s < 50) {
        f32x4 b4 = *reinterpret_cast<const f32x4*>(q2b + s * 16 + q * 4);
#pragma unroll
        for (int rl = 0; rl < 2; ++rl) {
          unsigned int w = pk_fp8x4(tanh_fast(acc2[si][rl][0] + b4.x),
                                    tanh_fast(acc2[si][rl][1] + b4.y),
                                    tanh_fast(acc2[si][rl][2] + b4.z),
                                    tanh_fast(acc2[si][rl][3] + b4.w));
          *reinterpret_cast<unsigned int*>(
              sHb + ((2 * p + rl) * 16 + srow) * 824 + s * 16 + q * 4) = w;
        }
      }
    }
  };
  gemm2_read(0);
  __syncthreads();          // all pass-0 reads of h1 rows 0-31 done
  gemm2_write(0);           // writes rows 0-31 (disjoint from pass-1 reads)
  gemm2_read(1);
  __syncthreads();          // all pass-1 reads of h1 rows 32-63 done
  gemm2_write(1);
  __syncthreads();          // h2 complete

  // ---- GEMM3: mu (strip wid), logsigma (strip wid+8); kld; mu -> sMuB swizzled ----
  f32x4 acc3[2][4];
#pragma unroll
  for (int t = 0; t < 2; ++t)
#pragma unroll
    for (int rf = 0; rf < 4; ++rf) acc3[t][rf] = fzero();
  const char* hb0 = reinterpret_cast<const char*>(headp8) + ((size_t)wid * 25) * 512 + l * 8;
  const char* hb1 = reinterpret_cast<const char*>(headp8) + ((size_t)(wid + 8) * 25) * 512 + l * 8;
#pragma unroll 5
  for (int ks = 0; ks < 25; ++ks) {
    long a8[4];
#pragma unroll
    for (int rf = 0; rf < 4; ++rf)
      a8[rf] = *reinterpret_cast<const long*>(sHb + (rf * 16 + srow) * 824 + ks * 32 + q * 8);
    long w0 = *reinterpret_cast<const long*>(hb0 + ks * 512);
    long w1 = *reinterpret_cast<const long*>(hb1 + ks * 512);
#pragma unroll
    for (int rf = 0; rf < 4; ++rf) {
      acc3[0][rf] = mfma_fp8(w0, a8[rf], acc3[0][rf]);
      acc3[1][rf] = mfma_fp8(w1, a8[rf], acc3[1][rf]);
    }
  }
  {
    f32x4 mb4 = *reinterpret_cast<const f32x4*>(mub + wid * 16 + q * 4);
    f32x4 lb4 = *reinterpret_cast<const f32x4*>(lsb + wid * 16 + q * 4);
    unsigned swz = ((unsigned)(srow & 7)) << 5;
    unsigned coff = ((unsigned)(wid * 32 + q * 8)) ^ swz;
    float kldp = 0.f;
#pragma unroll
    for (int rf = 0; rf < 4; ++rf) {
      float m0 = acc3[0][rf][0] + mb4.x, m1 = acc3[0][rf][1] + mb4.y;
      float m2 = acc3[0][rf][2] + mb4.z, m3 = acc3[0][rf][3] + mb4.w;
      kldp -= m0 * m0 + m1 * m1 + m2 * m2 + m3 * m3;
      u32x2 o;
      o.x = cvt_pk_bf16(m0, m1);
      o.y = cvt_pk_bf16(m2, m3);
      *reinterpret_cast<u32x2*>(sMuB + (rf * 16 + srow) * 256 + coff) = o;
      float v0 = acc3[1][rf][0] + lb4.x, v1 = acc3[1][rf][1] + lb4.y;
      float v2 = acc3[1][rf][2] + lb4.z, v3 = acc3[1][rf][3] + lb4.w;
      kldp += 4.f + v0 + v1 + v2 + v3
            - exp2f(v0 * LOG2E) - exp2f(v1 * LOG2E)
            - exp2f(v2 * LOG2E) - exp2f(v3 * LOG2E);
    }
#pragma unroll
    for (int d = 1; d < 64; d <<= 1) kldp += __shfl_xor(kldp, d);
    if (l == 0) sRed[wid] = kldp;
  }
  __syncthreads();

  // ---- decode: lane = (row rg, topic-group tg of 16); 9 shuffles total ----
  {
    const int2* bi2 = reinterpret_cast<const int2*>(bi_idx);
    const int rg = l >> 3, tg = l & 7;
    const int r = wid * 8 + rg;
    int2 bi = bi2[row0 + r];
    unsigned moff = ((unsigned)(tg * 32)) ^ (((unsigned)(r & 7)) << 5);
    const char* mrow = reinterpret_cast<const char*>(sMuB) + r * 256;
    u32x4 mwa = *reinterpret_cast<const u32x4*>(mrow + moff);
    u32x4 mwb = *reinterpret_cast<const u32x4*>(mrow + (moff ^ 16));
    const char* EtbB = reinterpret_cast<const char*>(Etb);
    u32x4 e0a = *reinterpret_cast<const u32x4*>(EtbB + (size_t)bi.x * 256 + tg * 32);
    u32x4 e0b = *reinterpret_cast<const u32x4*>(EtbB + (size_t)bi.x * 256 + tg * 32 + 16);
    u32x4 e1a = *reinterpret_cast<const u32x4*>(EtbB + (size_t)bi.y * 256 + tg * 32);
    u32x4 e1b = *reinterpret_cast<const u32x4*>(EtbB + (size_t)bi.y * 256 + tg * 32 + 16);
    float ivf[16];
#pragma unroll
    for (int j = 0; j < 4; ++j) {
      f32x4 v = *reinterpret_cast<const f32x4*>(sInv + tg * 16 + j * 4);
      ivf[4 * j] = v.x; ivf[4 * j + 1] = v.y; ivf[4 * j + 2] = v.z; ivf[4 * j + 3] = v.w;
    }
    unsigned mw[8]  = {mwa.x, mwa.y, mwa.z, mwa.w, mwb.x, mwb.y, mwb.z, mwb.w};
    unsigned ew0[8] = {e0a.x, e0a.y, e0a.z, e0a.w, e0b.x, e0b.y, e0b.z, e0b.w};
    unsigned ew1[8] = {e1a.x, e1a.y, e1a.z, e1a.w, e1b.x, e1b.y, e1b.z, e1b.w};
    float den = 0.f, pacc = 0.f;
#pragma unroll
    for (int i = 0; i < 8; ++i) {
      float ta = exp2f(bf_lo(mw[i]) * LOG2E);
      float tb = exp2f(bf_hi(mw[i]) * LOG2E);
      den += ta + tb;
      float ea = bf_lo(ew0[i]) * bf_lo(ew1[i]);
      float eb = bf_hi(ew0[i]) * bf_hi(ew1[i]);
      pacc += ta * ta * ea * ivf[2 * i] + tb * tb * eb * ivf[2 * i + 1];
    }
    den  += __shfl_xor(den, 1);  pacc += __shfl_xor(pacc, 1);
    den  += __shfl_xor(den, 2);  pacc += __shfl_xor(pacc, 2);
    den  += __shfl_xor(den, 4);  pacc += __shfl_xor(pacc, 4);
    float lr = 0.f;
    if (tg == 0)
      lr = fast_log(pacc * __builtin_amdgcn_rcpf(den * den) + 1e-6f);
    lr += __shfl_xor(lr, 8);
    lr += __shfl_xor(lr, 16);
    lr += __shfl_xor(lr, 32);
    if (l == 0) sRed[8 + wid] = lr;
  }
  __syncthreads();
  if (tid == 0) {
    float k = 0.f, s = 0.f;
#pragma unroll
    for (int i = 0; i < 8; ++i) { k += sRed[i]; s += sRed[8 + i]; }
    atomicAdd(&partial[1], k);
    atomicAdd(&partial[0], s);
  }
}

__global__ void finalize_kernel(const float* __restrict__ partial, float* __restrict__ out) {
  if (threadIdx.x == 0) {
    out[0] = partial[0] / (float)B_;
    out[1] = -0.5f * partial[1] / (float)B_;
  }
}

extern "C" void kernel_launch(void* const* d_in, const int* in_sizes, int n_in,
                              void* d_out, int out_size, void* d_ws, size_t ws_size,
                              hipStream_t stream) {
  const int*   bi_idx   = (const int*)d_in[0];
  const float* biterms  = (const float*)d_in[1];
  const float* rho      = (const float*)d_in[2];
  const float* alphas_W = (const float*)d_in[3];
  const float* q1_W     = (const float*)d_in[4];
  const float* q1_b     = (const float*)d_in[5];
  const float* q2_W     = (const float*)d_in[6];
  const float* q2_b     = (const float*)d_in[7];
  const float* mu_W     = (const float*)d_in[8];
  const float* mu_b     = (const float*)d_in[9];
  const float* ls_W     = (const float*)d_in[10];
  const float* ls_b     = (const float*)d_in[11];

  char* ws = (char*)d_ws;
  unsigned short* Etb   = (unsigned short*)(ws + OFF_ETB);
  float* colsum  = (float*)(ws + OFF_COLSUM);
  float* partial = (float*)(ws + OFF_PART);
  unsigned char*  q1p8  = (unsigned char*)(ws + OFF_Q1P8);
  unsigned char*  q2p8  = (unsigned char*)(ws + OFF_Q2P8);
  unsigned char*  headp8= (unsigned char*)(ws + OFF_HEADP8);
  unsigned short* alphap= (unsigned short*)(ws + OFF_ALP);
  unsigned char*  xp8   = (unsigned char*)(ws + OFF_XP8);

  hipMemsetAsync(ws + OFF_COLSUM, 0, 1024, stream);  // colsum + partials

  pack_x_fp8_kernel<<<(B_ / 16) * 10, 64, 0, stream>>>(biterms, xp8);
  pack_b_kernel<<<8 * 10, 64, 0, stream>>>(alphas_W, E_, K_, 10, alphap);
  pack_b_fp8_kernel<<<50 * 10, 64, 0, stream>>>(q1_W, E_, H_, 10, q1p8);
  pack_b_fp8_kernel<<<50 * 25, 64, 0, stream>>>(q2_W, H_, H_, 25, q2p8);
  pack_b_fp8_kernel<<<8 * 25, 64, 0, stream>>>(mu_W, H_, K_, 25, headp8);
  pack_b_fp8_kernel<<<8 * 25, 64, 0, stream>>>(ls_W, H_, K_, 25, headp8 + (size_t)200 * 512);

  tb_kernel<<<782, 512, 0, stream>>>(rho, alphap, Etb, colsum);

  fused_kernel<<<B_ / 64, 512, 0, stream>>>(bi_idx, q1_b, q2_b, mu_b, ls_b,
                                            xp8, q1p8, q2p8, headp8, Etb, colsum, partial);

  finalize_kernel<<<1, 64, 0, stream>>>(partial, (float*)d_out);
}

// Round 5
// 491.463 us; speedup vs baseline: 1.5856x; 1.1354x over previous
//
#include <hip/hip_runtime.h>
#include <hip/hip_bf16.h>

// Problem dims
#define V_ 50000
#define E_ 300
#define H_ 800
#define K_ 128
#define B_ 131072

typedef float  f32x4 __attribute__((ext_vector_type(4)));
typedef float  f32x2 __attribute__((ext_vector_type(2)));
typedef int    i32x4 __attribute__((ext_vector_type(4)));
typedef int    i32x8 __attribute__((ext_vector_type(8)));
typedef unsigned int u32x2 __attribute__((ext_vector_type(2)));
typedef unsigned int u32x4 __attribute__((ext_vector_type(4)));
typedef __bf16 bf16x8 __attribute__((ext_vector_type(8)));

#define LOG2E 1.4426950408889634f
#define HSTR 912   // LDS h stride bytes: 16B-aligned, (912/4)%32=4 -> 2-way bank phase (free)

// ---------------- ws layout (bytes) ----------------
static constexpr size_t OFF_ETB    = 0;                                  // bf16 [50048][128]
static constexpr size_t SZ_ETB     = (size_t)50048 * 128 * 2;            // 12,812,288
static constexpr size_t OFF_COLSUM = SZ_ETB;                             // 128 f32
static constexpr size_t OFF_PART   = OFF_COLSUM + 512;                   // partial[0]=loss, [1]=kld
static constexpr size_t OFF_Q1P8   = OFF_COLSUM + 1024;                  // 50 strips x 3 chunks x 2KB
static constexpr size_t OFF_Q2P8   = OFF_Q1P8 + (size_t)150 * 2048;      // 50 x 7 x 2KB
static constexpr size_t OFF_HEADP8 = OFF_Q2P8 + (size_t)350 * 2048;      // 16 x 7 x 2KB (mu 0-7, ls 8-15)
static constexpr size_t OFF_ALP    = OFF_HEADP8 + (size_t)112 * 2048;    // 8x10 bf16 frags (1KB)
static constexpr size_t OFF_XP8    = OFF_ALP + (size_t)80 * 1024;        // 8192 rfg x 3 chunks x 2KB

static __device__ __forceinline__ f32x4 mfma_bf16(i32x4 a, i32x4 b, f32x4 c) {
  return __builtin_amdgcn_mfma_f32_16x16x32_bf16(
      __builtin_bit_cast(bf16x8, a), __builtin_bit_cast(bf16x8, b), c, 0, 0, 0);
}
// MX-scaled fp8xfp8, K=128, all scales = 1.0 (E8M0 0x7F in every byte)
static __device__ __forceinline__ f32x4 mfma_mx(i32x8 a, i32x8 b, f32x4 c) {
  return __builtin_amdgcn_mfma_scale_f32_16x16x128_f8f6f4(
      a, b, c, 0 /*A=fp8*/, 0 /*B=fp8*/, 0, 0x7F7F7F7F, 0, 0x7F7F7F7F);
}

static __device__ __forceinline__ unsigned int cvt_pk_bf16(float a, float b) {
  unsigned int d;
  asm volatile("v_cvt_pk_bf16_f32 %0, %1, %2" : "=v"(d) : "v"(a), "v"(b));
  return d;
}
static __device__ __forceinline__ unsigned int pk_fp8x4(float a, float b, float c, float d) {
  int w = __builtin_amdgcn_cvt_pk_fp8_f32(a, b, 0, false);
  w = __builtin_amdgcn_cvt_pk_fp8_f32(c, d, w, true);
  return (unsigned int)w;
}

// tanh(x) = 1 - 2/(exp(2x)+1); correct limits at +/-inf without clamping.
static __device__ __forceinline__ float tanh_fast(float x) {
  float e = exp2f(x * 2.8853900817779268f);  // exp(2x)
  return __builtin_fmaf(-2.f, __builtin_amdgcn_rcpf(e + 1.f), 1.f);
}
static __device__ __forceinline__ float fast_log(float x) {
  return __builtin_amdgcn_logf(x) * 0.69314718056f;
}
static __device__ __forceinline__ float bf_lo(unsigned int w) {
  return __builtin_bit_cast(float, w << 16);
}
static __device__ __forceinline__ float bf_hi(unsigned int w) {
  return __builtin_bit_cast(float, w & 0xFFFF0000u);
}
static __device__ __forceinline__ f32x4 fzero() {
  f32x4 z; z.x = 0.f; z.y = 0.f; z.z = 0.f; z.w = 0.f; return z;
}
// 32B load as two 16B (works for 16B-aligned LDS rows and global frags)
static __device__ __forceinline__ i32x8 ld32B(const void* p) {
  i32x4 a = *reinterpret_cast<const i32x4*>(p);
  i32x4 b = *reinterpret_cast<const i32x4*>(reinterpret_cast<const char*>(p) + 16);
  return __builtin_shufflevector(a, b, 0, 1, 2, 3, 4, 5, 6, 7);
}

// ---------- pack biterms -> MX fp8 x-fragments ----------
// frag fi=(rfg*3+c): lane l holds X[rfg*16+(l&15)][c*128+(l>>4)*32 + r*4+t], zero >=300
__global__ void pack_x_mx_kernel(const float* __restrict__ X, unsigned char* __restrict__ dst) {
  int fi = blockIdx.x * 4 + (threadIdx.x >> 6);
  int l = threadIdx.x & 63;
  int rfg = fi / 3, c = fi - rfg * 3;
  int row = rfg * 16 + (l & 15);
  int k0 = c * 128 + ((l >> 4) << 5);
  const float* p = X + (size_t)row * 300 + k0;
  unsigned int o[8];
#pragma unroll
  for (int g = 0; g < 8; ++g) {
    f32x4 v = fzero();
    if (k0 + g * 4 < 300) v = *reinterpret_cast<const f32x4*>(p + g * 4);
    o[g] = pk_fp8x4(v.x, v.y, v.z, v.w);
  }
  *reinterpret_cast<u32x4*>(dst + (size_t)fi * 2048 + l * 32) =
      *reinterpret_cast<u32x4*>(&o[0]);
  *reinterpret_cast<u32x4*>(dst + (size_t)fi * 2048 + l * 32 + 16) =
      *reinterpret_cast<u32x4*>(&o[4]);
}

// ---------- pack W [Kdim][N] -> MX fp8 frags (2KB each) ----------
__global__ void pack_w_mx_kernel(const float* __restrict__ W, int Kdim, int N, int nc,
                                 unsigned char* __restrict__ dst) {
  int b = blockIdx.x, l = threadIdx.x;
  int sl = b / nc, c = b - sl * nc;
  int n = sl * 16 + (l & 15);
  int k0 = c * 128 + ((l >> 4) << 5);
  unsigned int o[8];
#pragma unroll
  for (int r = 0; r < 8; ++r) {
    float t[4];
#pragma unroll
    for (int tt = 0; tt < 4; ++tt) {
      int k = k0 + r * 4 + tt;
      t[tt] = (k < Kdim) ? W[(size_t)k * N + n] : 0.f;
    }
    o[r] = pk_fp8x4(t[0], t[1], t[2], t[3]);
  }
  *reinterpret_cast<u32x4*>(dst + (size_t)b * 2048 + l * 32) =
      *reinterpret_cast<u32x4*>(&o[0]);
  *reinterpret_cast<u32x4*>(dst + (size_t)b * 2048 + l * 32 + 16) =
      *reinterpret_cast<u32x4*>(&o[4]);
}

// ---------- pack W [Kdim][N] -> bf16 K32 frags (for tb alphas) ----------
__global__ void pack_b_kernel(const float* __restrict__ W, int Kdim, int N, int nks,
                              unsigned short* __restrict__ dst) {
  int b = blockIdx.x, l = threadIdx.x;
  int sl = b / nks, ks = b % nks;
  int n = sl * 16 + (l & 15);
  int k0 = ks * 32 + (l >> 4) * 8;
  float t[8];
#pragma unroll
  for (int i = 0; i < 8; ++i) {
    int k = k0 + i;
    t[i] = (k < Kdim) ? W[(size_t)k * N + n] : 0.f;
  }
  i32x4 o;
  o.x = (int)cvt_pk_bf16(t[0], t[1]);
  o.y = (int)cvt_pk_bf16(t[2], t[3]);
  o.z = (int)cvt_pk_bf16(t[4], t[5]);
  o.w = (int)cvt_pk_bf16(t[6], t[7]);
  *reinterpret_cast<i32x4*>(dst + (size_t)b * 512 + l * 8) = o;
}

// ---------- tb kernel: Etb(bf16) = exp(rho @ alphas), colsum over vocab ----------
__global__ __launch_bounds__(512) void tb_kernel(
    const float* __restrict__ rho, const unsigned short* __restrict__ alphap,
    unsigned short* __restrict__ Etb, float* __restrict__ colsum) {
  int tid = threadIdx.x;
  int wid = tid >> 6, l = tid & 63;
  int srow = l & 15, q = l >> 4;
  int tile = blockIdx.x;
  const i32x4* ap = reinterpret_cast<const i32x4*>(alphap);
  f32x4 acc[4];
#pragma unroll
  for (int rf = 0; rf < 4; ++rf) acc[rf] = fzero();
  for (int ks = 0; ks < 10; ++ks) {
    i32x4 aw = ap[((size_t)wid * 10 + ks) * 64 + l];
#pragma unroll
    for (int rf = 0; rf < 4; ++rf) {
      int row = tile * 64 + rf * 16 + srow;
      f32x4 v0 = fzero(), v1 = fzero();
      if (row < V_) {
        const float* p = rho + (size_t)row * 300 + ks * 32 + q * 8;
        if (ks < 9) {
          v0 = *reinterpret_cast<const f32x4*>(p);
          v1 = *reinterpret_cast<const f32x4*>(p + 4);
        } else {
          if (q < 2)  v0 = *reinterpret_cast<const f32x4*>(p);
          if (q == 0) v1 = *reinterpret_cast<const f32x4*>(p + 4);
        }
      }
      i32x4 rv;
      rv.x = (int)cvt_pk_bf16(v0.x, v0.y);
      rv.y = (int)cvt_pk_bf16(v0.z, v0.w);
      rv.z = (int)cvt_pk_bf16(v1.x, v1.y);
      rv.w = (int)cvt_pk_bf16(v1.z, v1.w);
      acc[rf] = mfma_bf16(aw, rv, acc[rf]);
    }
  }
  float cs[4] = {0.f, 0.f, 0.f, 0.f};
#pragma unroll
  for (int rf = 0; rf < 4; ++rf) {
    int row = tile * 64 + rf * 16 + srow;
    float e0 = exp2f(acc[rf][0] * LOG2E);
    float e1 = exp2f(acc[rf][1] * LOG2E);
    float e2 = exp2f(acc[rf][2] * LOG2E);
    float e3 = exp2f(acc[rf][3] * LOG2E);
    if (row < V_) {
      u32x2 o;
      o.x = cvt_pk_bf16(e0, e1);
      o.y = cvt_pk_bf16(e2, e3);
      *reinterpret_cast<u32x2*>(Etb + (size_t)row * 128 + wid * 16 + q * 4) = o;
      cs[0] += e0; cs[1] += e1; cs[2] += e2; cs[3] += e3;
    }
  }
#pragma unroll
  for (int d = 1; d < 16; d <<= 1) {
#pragma unroll
    for (int r = 0; r < 4; ++r) cs[r] += __shfl_xor(cs[r], d);
  }
  if (srow == 0) {
#pragma unroll
    for (int r = 0; r < 4; ++r) atomicAdd(&colsum[wid * 16 + q * 4 + r], cs[r]);
  }
}

// ---------- fused main kernel: 64 rows/block, 8 waves, 2 blocks/CU, MX fp8 ----------
__global__ __launch_bounds__(512, 2) void fused_kernel(
    const int* __restrict__ bi_idx,
    const float* __restrict__ q1b, const float* __restrict__ q2b,
    const float* __restrict__ mub, const float* __restrict__ lsb,
    const unsigned char* __restrict__ xp8, const unsigned char* __restrict__ q1p8,
    const unsigned char* __restrict__ q2p8, const unsigned char* __restrict__ headp8,
    const unsigned short* __restrict__ Etb, const float* __restrict__ colsum,
    float* __restrict__ partial) {
  __shared__ __align__(16) unsigned char sH[64 * HSTR];   // 58,368 B (fp8 h1/h2, 896 cols)
  __shared__ __align__(16) unsigned char sMuB[64 * 256];  // 16,384 B (bf16 mu, XOR-swizzled)
  __shared__ __align__(16) float sInv[128];
  __shared__ float sRed[16];

  const int tid = threadIdx.x, wid = tid >> 6, l = tid & 63;
  const int srow = l & 15, q = l >> 4;
  const int row0 = blockIdx.x * 64;

  if (tid < 128) { float c = colsum[tid]; sInv[tid] = 1.f / (c * c); }
  char* sHb = reinterpret_cast<char*>(sH);
  // zero-fill h cols 800..895 (read by K=896 chunks, never overwritten)
  {
    int zr = tid >> 3, zs = tid & 7;
    unsigned int* zp = reinterpret_cast<unsigned int*>(sHb + zr * HSTR + 800 + zs * 12);
    zp[0] = 0u; zp[1] = 0u; zp[2] = 0u;
  }

  // ---- GEMM1: h1 = tanh(x @ q1 + b1) -> sH fp8; two 32-row passes; K=384 (3 chunks) ----
  const char* q1base[7];
#pragma unroll
  for (int si = 0; si < 7; ++si)
    q1base[si] = reinterpret_cast<const char*>(q1p8) +
                 (size_t)(wid + 8 * si) * 3 * 2048 + l * 32;
  auto gemm1_pass = [&](int p) {
    f32x4 acc1[7][2];
#pragma unroll
    for (int si = 0; si < 7; ++si) { acc1[si][0] = fzero(); acc1[si][1] = fzero(); }
    const char* xbase = reinterpret_cast<const char*>(xp8) +
                        (size_t)(blockIdx.x * 4 + 2 * p) * 3 * 2048 + l * 32;
#pragma unroll
    for (int c = 0; c < 3; ++c) {
      i32x8 x0 = ld32B(xbase + c * 2048);
      i32x8 x1 = ld32B(xbase + (3 + c) * 2048);
#pragma unroll
      for (int si = 0; si < 7; ++si) {
        if (wid + 8 * si < 50) {
          i32x8 w = ld32B(q1base[si] + c * 2048);
          acc1[si][0] = mfma_mx(w, x0, acc1[si][0]);
          acc1[si][1] = mfma_mx(w, x1, acc1[si][1]);
        }
      }
    }
#pragma unroll
    for (int si = 0; si < 7; ++si) {
      int s = wid + 8 * si;
      if (s < 50) {
        f32x4 b4 = *reinterpret_cast<const f32x4*>(q1b + s * 16 + q * 4);
#pragma unroll
        for (int rl = 0; rl < 2; ++rl) {
          unsigned int w = pk_fp8x4(tanh_fast(acc1[si][rl][0] + b4.x),
                                    tanh_fast(acc1[si][rl][1] + b4.y),
                                    tanh_fast(acc1[si][rl][2] + b4.z),
                                    tanh_fast(acc1[si][rl][3] + b4.w));
          *reinterpret_cast<unsigned int*>(
              sHb + ((2 * p + rl) * 16 + srow) * HSTR + s * 16 + q * 4) = w;
        }
      }
    }
  };
  gemm1_pass(0);
  gemm1_pass(1);
  __syncthreads();

  // ---- GEMM2: h2 = tanh(h1 @ q2 + b2), in-place over sH; K=896 (7 chunks) ----
  const char* q2base[7];
#pragma unroll
  for (int si = 0; si < 7; ++si)
    q2base[si] = reinterpret_cast<const char*>(q2p8) +
                 (size_t)(wid + 8 * si) * 7 * 2048 + l * 32;
  f32x4 acc2[7][2];
  auto gemm2_read = [&](int p) {
#pragma unroll
    for (int si = 0; si < 7; ++si) { acc2[si][0] = fzero(); acc2[si][1] = fzero(); }
    for (int c = 0; c < 7; ++c) {
      i32x8 h0 = ld32B(sHb + ((2 * p + 0) * 16 + srow) * HSTR + c * 128 + q * 32);
      i32x8 h1 = ld32B(sHb + ((2 * p + 1) * 16 + srow) * HSTR + c * 128 + q * 32);
#pragma unroll
      for (int si = 0; si < 7; ++si) {
        if (wid + 8 * si < 50) {
          i32x8 w = ld32B(q2base[si] + c * 2048);
          acc2[si][0] = mfma_mx(w, h0, acc2[si][0]);
          acc2[si][1] = mfma_mx(w, h1, acc2[si][1]);
        }
      }
    }
  };
  auto gemm2_write = [&](int p) {
#pragma unroll
    for (int si = 0; si < 7; ++si) {
      int s = wid + 8 * si;
      if (s < 50) {
        f32x4 b4 = *reinterpret_cast<const f32x4*>(q2b + s * 16 + q * 4);
#pragma unroll
        for (int rl = 0; rl < 2; ++rl) {
          unsigned int w = pk_fp8x4(tanh_fast(acc2[si][rl][0] + b4.x),
                                    tanh_fast(acc2[si][rl][1] + b4.y),
                                    tanh_fast(acc2[si][rl][2] + b4.z),
                                    tanh_fast(acc2[si][rl][3] + b4.w));
          *reinterpret_cast<unsigned int*>(
              sHb + ((2 * p + rl) * 16 + srow) * HSTR + s * 16 + q * 4) = w;
        }
      }
    }
  };
  gemm2_read(0);
  __syncthreads();          // all pass-0 reads of h1 rows 0-31 done
  gemm2_write(0);           // writes rows 0-31 cols<800 (disjoint from pass-1 reads)
  gemm2_read(1);
  __syncthreads();          // all pass-1 reads of h1 rows 32-63 done
  gemm2_write(1);
  __syncthreads();          // h2 complete

  // ---- GEMM3: mu (strip wid), logsigma (strip wid+8); kld; mu -> sMuB swizzled ----
  f32x4 acc3[2][4];
#pragma unroll
  for (int t = 0; t < 2; ++t)
#pragma unroll
    for (int rf = 0; rf < 4; ++rf) acc3[t][rf] = fzero();
  const char* hb0 = reinterpret_cast<const char*>(headp8) + (size_t)wid * 7 * 2048 + l * 32;
  const char* hb1 = reinterpret_cast<const char*>(headp8) + (size_t)(wid + 8) * 7 * 2048 + l * 32;
  for (int c = 0; c < 7; ++c) {
    i32x8 a8[4];
#pragma unroll
    for (int rf = 0; rf < 4; ++rf)
      a8[rf] = ld32B(sHb + (rf * 16 + srow) * HSTR + c * 128 + q * 32);
    i32x8 w0 = ld32B(hb0 + c * 2048);
    i32x8 w1 = ld32B(hb1 + c * 2048);
#pragma unroll
    for (int rf = 0; rf < 4; ++rf) {
      acc3[0][rf] = mfma_mx(w0, a8[rf], acc3[0][rf]);
      acc3[1][rf] = mfma_mx(w1, a8[rf], acc3[1][rf]);
    }
  }
  {
    f32x4 mb4 = *reinterpret_cast<const f32x4*>(mub + wid * 16 + q * 4);
    f32x4 lb4 = *reinterpret_cast<const f32x4*>(lsb + wid * 16 + q * 4);
    unsigned swz = ((unsigned)(srow & 7)) << 5;
    unsigned coff = ((unsigned)(wid * 32 + q * 8)) ^ swz;
    float kldp = 0.f;
#pragma unroll
    for (int rf = 0; rf < 4; ++rf) {
      float m0 = acc3[0][rf][0] + mb4.x, m1 = acc3[0][rf][1] + mb4.y;
      float m2 = acc3[0][rf][2] + mb4.z, m3 = acc3[0][rf][3] + mb4.w;
      kldp -= m0 * m0 + m1 * m1 + m2 * m2 + m3 * m3;
      u32x2 o;
      o.x = cvt_pk_bf16(m0, m1);
      o.y = cvt_pk_bf16(m2, m3);
      *reinterpret_cast<u32x2*>(sMuB + (rf * 16 + srow) * 256 + coff) = o;
      float v0 = acc3[1][rf][0] + lb4.x, v1 = acc3[1][rf][1] + lb4.y;
      float v2 = acc3[1][rf][2] + lb4.z, v3 = acc3[1][rf][3] + lb4.w;
      kldp += 4.f + v0 + v1 + v2 + v3
            - exp2f(v0 * LOG2E) - exp2f(v1 * LOG2E)
            - exp2f(v2 * LOG2E) - exp2f(v3 * LOG2E);
    }
#pragma unroll
    for (int d = 1; d < 64; d <<= 1) kldp += __shfl_xor(kldp, d);
    if (l == 0) sRed[wid] = kldp;
  }
  __syncthreads();

  // ---- decode: lane = (row rg=l>>3, topic-group tg=l&7 of 16 topics) ----
  {
    const int2* bi2 = reinterpret_cast<const int2*>(bi_idx);
    const int rg = l >> 3, tg = l & 7;
    const int r = wid * 8 + rg;
    int2 bi = bi2[row0 + r];
    unsigned moff = ((unsigned)(tg * 32)) ^ (((unsigned)(r & 7)) << 5);
    const char* mrow = reinterpret_cast<const char*>(sMuB) + r * 256;
    u32x4 mwa = *reinterpret_cast<const u32x4*>(mrow + moff);
    u32x4 mwb = *reinterpret_cast<const u32x4*>(mrow + (moff ^ 16));
    const char* EtbB = reinterpret_cast<const char*>(Etb);
    u32x4 e0a = *reinterpret_cast<const u32x4*>(EtbB + (size_t)bi.x * 256 + tg * 32);
    u32x4 e0b = *reinterpret_cast<const u32x4*>(EtbB + (size_t)bi.x * 256 + tg * 32 + 16);
    u32x4 e1a = *reinterpret_cast<const u32x4*>(EtbB + (size_t)bi.y * 256 + tg * 32);
    u32x4 e1b = *reinterpret_cast<const u32x4*>(EtbB + (size_t)bi.y * 256 + tg * 32 + 16);
    float ivf[16];
#pragma unroll
    for (int j = 0; j < 4; ++j) {
      f32x4 v = *reinterpret_cast<const f32x4*>(sInv + tg * 16 + j * 4);
      ivf[4 * j] = v.x; ivf[4 * j + 1] = v.y; ivf[4 * j + 2] = v.z; ivf[4 * j + 3] = v.w;
    }
    unsigned mw[8]  = {mwa.x, mwa.y, mwa.z, mwa.w, mwb.x, mwb.y, mwb.z, mwb.w};
    unsigned ew0[8] = {e0a.x, e0a.y, e0a.z, e0a.w, e0b.x, e0b.y, e0b.z, e0b.w};
    unsigned ew1[8] = {e1a.x, e1a.y, e1a.z, e1a.w, e1b.x, e1b.y, e1b.z, e1b.w};
    float den = 0.f, pacc = 0.f;
#pragma unroll
    for (int i = 0; i < 8; ++i) {
      float ta = exp2f(bf_lo(mw[i]) * LOG2E);
      float tb = exp2f(bf_hi(mw[i]) * LOG2E);
      den += ta + tb;
      float ea = bf_lo(ew0[i]) * bf_lo(ew1[i]);
      float eb = bf_hi(ew0[i]) * bf_hi(ew1[i]);
      pacc += ta * ta * ea * ivf[2 * i] + tb * tb * eb * ivf[2 * i + 1];
    }
    den  += __shfl_xor(den, 1);  pacc += __shfl_xor(pacc, 1);
    den  += __shfl_xor(den, 2);  pacc += __shfl_xor(pacc, 2);
    den  += __shfl_xor(den, 4);  pacc += __shfl_xor(pacc, 4);
    float lr = 0.f;
    if (tg == 0)
      lr = fast_log(pacc * __builtin_amdgcn_rcpf(den * den) + 1e-6f);
    lr += __shfl_xor(lr, 8);
    lr += __shfl_xor(lr, 16);
    lr += __shfl_xor(lr, 32);
    if (l == 0) sRed[8 + wid] = lr;
  }
  __syncthreads();
  if (tid == 0) {
    float k = 0.f, s = 0.f;
#pragma unroll
    for (int i = 0; i < 8; ++i) { k += sRed[i]; s += sRed[8 + i]; }
    atomicAdd(&partial[1], k);
    atomicAdd(&partial[0], s);
  }
}

__global__ void finalize_kernel(const float* __restrict__ partial, float* __restrict__ out) {
  if (threadIdx.x == 0) {
    out[0] = partial[0] / (float)B_;
    out[1] = -0.5f * partial[1] / (float)B_;
  }
}

extern "C" void kernel_launch(void* const* d_in, const int* in_sizes, int n_in,
                              void* d_out, int out_size, void* d_ws, size_t ws_size,
                              hipStream_t stream) {
  const int*   bi_idx   = (const int*)d_in[0];
  const float* biterms  = (const float*)d_in[1];
  const float* rho      = (const float*)d_in[2];
  const float* alphas_W = (const float*)d_in[3];
  const float* q1_W     = (const float*)d_in[4];
  const float* q1_b     = (const float*)d_in[5];
  const float* q2_W     = (const float*)d_in[6];
  const float* q2_b     = (const float*)d_in[7];
  const float* mu_W     = (const float*)d_in[8];
  const float* mu_b     = (const float*)d_in[9];
  const float* ls_W     = (const float*)d_in[10];
  const float* ls_b     = (const float*)d_in[11];

  char* ws = (char*)d_ws;
  unsigned short* Etb   = (unsigned short*)(ws + OFF_ETB);
  float* colsum  = (float*)(ws + OFF_COLSUM);
  float* partial = (float*)(ws + OFF_PART);
  unsigned char*  q1p8  = (unsigned char*)(ws + OFF_Q1P8);
  unsigned char*  q2p8  = (unsigned char*)(ws + OFF_Q2P8);
  unsigned char*  headp8= (unsigned char*)(ws + OFF_HEADP8);
  unsigned short* alphap= (unsigned short*)(ws + OFF_ALP);
  unsigned char*  xp8   = (unsigned char*)(ws + OFF_XP8);

  hipMemsetAsync(ws + OFF_COLSUM, 0, 1024, stream);  // colsum + partials

  pack_x_mx_kernel<<<(B_ / 16) * 3 / 4, 256, 0, stream>>>(biterms, xp8);
  pack_b_kernel<<<8 * 10, 64, 0, stream>>>(alphas_W, E_, K_, 10, alphap);
  pack_w_mx_kernel<<<50 * 3, 64, 0, stream>>>(q1_W, E_, H_, 3, q1p8);
  pack_w_mx_kernel<<<50 * 7, 64, 0, stream>>>(q2_W, H_, H_, 7, q2p8);
  pack_w_mx_kernel<<<8 * 7, 64, 0, stream>>>(mu_W, H_, K_, 7, headp8);
  pack_w_mx_kernel<<<8 * 7, 64, 0, stream>>>(ls_W, H_, K_, 7, headp8 + (size_t)56 * 2048);

  tb_kernel<<<782, 512, 0, stream>>>(rho, alphap, Etb, colsum);

  fused_kernel<<<B_ / 64, 512, 0, stream>>>(bi_idx, q1_b, q2_b, mu_b, ls_b,
                                            xp8, q1p8, q2p8, headp8, Etb, colsum, partial);

  finalize_kernel<<<1, 64, 0, stream>>>(partial, (float*)d_out);
}